// Round 1
// baseline (99.586 us; speedup 1.0000x reference)
//
#include <hip/hip_runtime.h>
#include <stdint.h>

#define N_ROWS 8192
#define DIM 256

constexpr float INV_T  = 1.0f / 0.07f;
constexpr float DIAG_T = -10.0f / 0.07f;

typedef __bf16 bf16x8 __attribute__((ext_vector_type(8)));
typedef float  f32x4  __attribute__((ext_vector_type(4)));

__device__ inline unsigned short f32_to_bf16(float f) {
    union { float f; uint32_t u; } v; v.f = f;
    uint32_t u = v.u;
    u += 0x7FFFu + ((u >> 16) & 1u);   // round-to-nearest-even
    return (unsigned short)(u >> 16);
}

// ---------------- Kernel 1: norms + l_pos + bf16 cast ----------------
__global__ __launch_bounds__(64) void prep_kernel(
    const float* __restrict__ q, const float* __restrict__ k,
    unsigned short* __restrict__ qb, unsigned short* __restrict__ kb,
    float* __restrict__ invq, float* __restrict__ invk,
    float* __restrict__ lposT) {
    const int row  = blockIdx.x;
    const int lane = threadIdx.x;

    const float4 qv = *reinterpret_cast<const float4*>(q + (size_t)row * DIM + lane * 4);
    const float4 kv = *reinterpret_cast<const float4*>(k + (size_t)row * DIM + lane * 4);

    float qq = qv.x*qv.x + qv.y*qv.y + qv.z*qv.z + qv.w*qv.w;
    float kk = kv.x*kv.x + kv.y*kv.y + kv.z*kv.z + kv.w*kv.w;
    float qk = qv.x*kv.x + qv.y*kv.y + qv.z*kv.z + qv.w*kv.w;

    ushort4 qs, ks;
    qs.x = f32_to_bf16(qv.x); qs.y = f32_to_bf16(qv.y);
    qs.z = f32_to_bf16(qv.z); qs.w = f32_to_bf16(qv.w);
    ks.x = f32_to_bf16(kv.x); ks.y = f32_to_bf16(kv.y);
    ks.z = f32_to_bf16(kv.z); ks.w = f32_to_bf16(kv.w);
    *reinterpret_cast<ushort4*>(qb + (size_t)row * DIM + lane * 4) = qs;
    *reinterpret_cast<ushort4*>(kb + (size_t)row * DIM + lane * 4) = ks;

    #pragma unroll
    for (int off = 32; off > 0; off >>= 1) {
        qq += __shfl_xor(qq, off, 64);
        kk += __shfl_xor(kk, off, 64);
        qk += __shfl_xor(qk, off, 64);
    }
    if (lane == 0) {
        float iq = 1.0f / sqrtf(qq);
        float ik = 1.0f / sqrtf(kk);
        invq[row]  = iq;
        invk[row]  = ik;
        lposT[row] = qk * iq * ik * INV_T;
    }
}

// ---------------- Kernel 2: 128x128 bf16 MFMA GEMM + partial LSE ----------------
__global__ __launch_bounds__(256) void gemm_lse_kernel(
    const unsigned short* __restrict__ qb, const unsigned short* __restrict__ kb,
    const float* __restrict__ invq, const float* __restrict__ invk,
    float* __restrict__ pm, float* __restrict__ ps) {
    __shared__ unsigned short Qs[128 * 64];   // [row][k] bf16, 16 KB
    __shared__ unsigned short Ks[128 * 64];
    __shared__ float redM[128][2];
    __shared__ float redS[128][2];

    const int tid   = threadIdx.x;
    const int lane  = tid & 63;
    const int wid   = tid >> 6;
    const int waveM = wid >> 1;     // 0..1
    const int waveN = wid & 1;      // 0..1
    const int rowBase = blockIdx.y * 128;
    const int colBase = blockIdx.x * 128;

    const int g   = lane >> 4;      // k-group 0..3
    const int r16 = lane & 15;

    // staging map: thread t -> row t/8 (of 32 per issue), 16B slot t%8
    const int srow  = tid >> 3;
    const int sslot = tid & 7;

    f32x4 acc[4][4] = {};

    for (int k0 = 0; k0 < DIM; k0 += 64) {
        #pragma unroll
        for (int i = 0; i < 4; ++i) {
            const int r = i * 32 + srow;
            const unsigned short* gq = qb + (size_t)(rowBase + r) * DIM + k0 + sslot * 8;
            const unsigned short* gk = kb + (size_t)(colBase + r) * DIM + k0 + sslot * 8;
            __builtin_amdgcn_global_load_lds(
                (const __attribute__((address_space(1))) void*)gq,
                (__attribute__((address_space(3))) void*)((char*)Qs + i * 4096 + wid * 1024),
                16, 0, 0);
            __builtin_amdgcn_global_load_lds(
                (const __attribute__((address_space(1))) void*)gk,
                (__attribute__((address_space(3))) void*)((char*)Ks + i * 4096 + wid * 1024),
                16, 0, 0);
        }
        __syncthreads();   // drains vmcnt before barrier

        #pragma unroll
        for (int kk = 0; kk < 2; ++kk) {
            bf16x8 a[4], b[4];
            #pragma unroll
            for (int m = 0; m < 4; ++m) {
                const int row = waveM * 64 + m * 16 + r16;
                a[m] = *reinterpret_cast<const bf16x8*>(&Qs[row * 64 + kk * 32 + g * 8]);
            }
            #pragma unroll
            for (int n = 0; n < 4; ++n) {
                const int row = waveN * 64 + n * 16 + r16;
                b[n] = *reinterpret_cast<const bf16x8*>(&Ks[row * 64 + kk * 32 + g * 8]);
            }
            #pragma unroll
            for (int m = 0; m < 4; ++m)
                #pragma unroll
                for (int n = 0; n < 4; ++n)
                    acc[m][n] = __builtin_amdgcn_mfma_f32_16x16x32_bf16(a[m], b[n], acc[m][n], 0, 0, 0);
        }
        __syncthreads();
    }

    // ---- epilogue: scale, diag fill, per-row (max, sum exp) partials ----
    float kscale[4];
    #pragma unroll
    for (int n = 0; n < 4; ++n)
        kscale[n] = invk[colBase + waveN * 64 + n * 16 + r16];

    float qscale[4][4];
    #pragma unroll
    for (int m = 0; m < 4; ++m)
        #pragma unroll
        for (int reg = 0; reg < 4; ++reg)
            qscale[m][reg] = invq[rowBase + waveM * 64 + m * 16 + g * 4 + reg] * INV_T;

    #pragma unroll
    for (int m = 0; m < 4; ++m) {
        #pragma unroll
        for (int reg = 0; reg < 4; ++reg) {
            const int grow = rowBase + waveM * 64 + m * 16 + g * 4 + reg;
            float vals[4];
            float rmax = -3.0e38f;
            #pragma unroll
            for (int n = 0; n < 4; ++n) {
                const int gcol = colBase + waveN * 64 + n * 16 + r16;
                float v = acc[m][n][reg] * qscale[m][reg] * kscale[n];
                if (grow == gcol) v = DIAG_T;
                vals[n] = v;
                rmax = fmaxf(rmax, v);
            }
            #pragma unroll
            for (int off = 1; off < 16; off <<= 1)
                rmax = fmaxf(rmax, __shfl_xor(rmax, off, 64));
            float sexp = 0.0f;
            #pragma unroll
            for (int n = 0; n < 4; ++n)
                sexp += __expf(vals[n] - rmax);
            #pragma unroll
            for (int off = 1; off < 16; off <<= 1)
                sexp += __shfl_xor(sexp, off, 64);
            if (r16 == 0) {
                const int rit = waveM * 64 + m * 16 + g * 4 + reg;
                redM[rit][waveN] = rmax;
                redS[rit][waveN] = sexp;
            }
        }
    }
    __syncthreads();

    if (tid < 128) {
        const float m0 = redM[tid][0], m1 = redM[tid][1];
        const float M  = fmaxf(m0, m1);
        const float S  = redS[tid][0] * __expf(m0 - M) + redS[tid][1] * __expf(m1 - M);
        const int grow = rowBase + tid;
        pm[(size_t)grow * 64 + blockIdx.x] = M;
        ps[(size_t)grow * 64 + blockIdx.x] = S;
    }
}

// ---------------- Kernel 3: combine partials -> loss ----------------
__global__ __launch_bounds__(64) void finalize_kernel(
    const float* __restrict__ pm, const float* __restrict__ ps,
    const float* __restrict__ lposT, float* __restrict__ out) {
    const int row  = blockIdx.x;
    const int lane = threadIdx.x;

    const float m  = pm[(size_t)row * 64 + lane];
    const float s  = ps[(size_t)row * 64 + lane];
    const float lp = lposT[row];

    float M = m;
    #pragma unroll
    for (int off = 1; off < 64; off <<= 1)
        M = fmaxf(M, __shfl_xor(M, off, 64));
    M = fmaxf(M, lp);

    float S = s * __expf(m - M);
    #pragma unroll
    for (int off = 1; off < 64; off <<= 1)
        S += __shfl_xor(S, off, 64);
    S += __expf(lp - M);

    if (lane == 0) out[row] = M + logf(S) - lp;
}

extern "C" void kernel_launch(void* const* d_in, const int* in_sizes, int n_in,
                              void* d_out, int out_size, void* d_ws, size_t ws_size,
                              hipStream_t stream) {
    const float* q = (const float*)d_in[0];
    const float* k = (const float*)d_in[1];
    float* out = (float*)d_out;

    char* ws = (char*)d_ws;
    unsigned short* qb   = (unsigned short*)(ws);                       // 4 MB
    unsigned short* kb   = (unsigned short*)(ws + (4u << 20));          // 4 MB
    float*          invq = (float*)(ws + (8u << 20));                   // 32 KB
    float*          invk = (float*)(ws + (8u << 20) + (32u << 10));     // 32 KB
    float*          lpt  = (float*)(ws + (8u << 20) + (64u << 10));     // 32 KB
    float*          pm   = (float*)(ws + (8u << 20) + (96u << 10));     // 2 MB
    float*          ps   = (float*)(ws + (10u << 20) + (96u << 10));    // 2 MB

    prep_kernel<<<N_ROWS, 64, 0, stream>>>(q, k, qb, kb, invq, invk, lpt);
    dim3 grid(N_ROWS / 128, N_ROWS / 128);
    gemm_lse_kernel<<<grid, 256, 0, stream>>>(qb, kb, invq, invk, pm, ps);
    finalize_kernel<<<N_ROWS, 64, 0, stream>>>(pm, ps, lpt, out);
}

// Round 2
// 64.583 us; speedup vs baseline: 1.5420x; 1.5420x over previous
//
#include <hip/hip_runtime.h>
#include <stdint.h>

#define N_ROWS 8192
#define DIM 256

constexpr float INV_T  = 1.0f / 0.07f;
constexpr float M0     = 1.0f / 0.07f;   // fixed LSE max: |cos sim| <= ~1

typedef __bf16 bf16x8 __attribute__((ext_vector_type(8)));
typedef float  f32x4  __attribute__((ext_vector_type(4)));

__device__ inline unsigned short f32_to_bf16(float f) {
    union { float f; uint32_t u; } v; v.f = f;
    uint32_t u = v.u;
    u += 0x7FFFu + ((u >> 16) & 1u);   // round-to-nearest-even
    return (unsigned short)(u >> 16);
}

// ---------------- Kernel 1: norms + l_pos + bf16 cast ----------------
__global__ __launch_bounds__(64) void prep_kernel(
    const float* __restrict__ q, const float* __restrict__ k,
    unsigned short* __restrict__ qb, unsigned short* __restrict__ kb,
    float* __restrict__ invq, float* __restrict__ invk,
    float* __restrict__ lposT) {
    const int row  = blockIdx.x;
    const int lane = threadIdx.x;

    const float4 qv = *reinterpret_cast<const float4*>(q + (size_t)row * DIM + lane * 4);
    const float4 kv = *reinterpret_cast<const float4*>(k + (size_t)row * DIM + lane * 4);

    float qq = qv.x*qv.x + qv.y*qv.y + qv.z*qv.z + qv.w*qv.w;
    float kk = kv.x*kv.x + kv.y*kv.y + kv.z*kv.z + kv.w*kv.w;
    float qk = qv.x*kv.x + qv.y*kv.y + qv.z*kv.z + qv.w*kv.w;

    ushort4 qs, ks;
    qs.x = f32_to_bf16(qv.x); qs.y = f32_to_bf16(qv.y);
    qs.z = f32_to_bf16(qv.z); qs.w = f32_to_bf16(qv.w);
    ks.x = f32_to_bf16(kv.x); ks.y = f32_to_bf16(kv.y);
    ks.z = f32_to_bf16(kv.z); ks.w = f32_to_bf16(kv.w);
    *reinterpret_cast<ushort4*>(qb + (size_t)row * DIM + lane * 4) = qs;
    *reinterpret_cast<ushort4*>(kb + (size_t)row * DIM + lane * 4) = ks;

    #pragma unroll
    for (int off = 32; off > 0; off >>= 1) {
        qq += __shfl_xor(qq, off, 64);
        kk += __shfl_xor(kk, off, 64);
        qk += __shfl_xor(qk, off, 64);
    }
    if (lane == 0) {
        float iq = 1.0f / sqrtf(qq);
        float ik = 1.0f / sqrtf(kk);
        invq[row]  = iq;
        invk[row]  = ik;
        lposT[row] = qk * iq * ik * INV_T;
    }
}

// ---------------- Kernel 2: 128x128 bf16 MFMA GEMM + fixed-max LSE partials ----
// Operand swap: A = K rows, B = Q rows  ->  D[k_idx][q_idx].
// Per lane: D col = lane&15 = Q row -> per-Q-row exp sums are lane-local.
__global__ __launch_bounds__(256) void gemm_lse_kernel(
    const unsigned short* __restrict__ qb, const unsigned short* __restrict__ kb,
    const float* __restrict__ invq, const float* __restrict__ invk,
    float* __restrict__ ps) {
    __shared__ unsigned short Qs[128 * 64];   // 16 KB, XOR-swizzled (slot ^ row&7)
    __shared__ unsigned short Ks[128 * 64];
    __shared__ float redS[128][2];

    const int tid   = threadIdx.x;
    const int lane  = tid & 63;
    const int wid   = tid >> 6;
    const int waveQ = wid & 1;      // Q half (B operand / D columns)
    const int waveK = wid >> 1;     // K half (A operand / D rows)
    const int rowBase = blockIdx.y * 128;   // Q rows
    const int colBase = blockIdx.x * 128;   // K rows (= logit columns)

    const int g   = lane >> 4;      // k-group 0..3
    const int r16 = lane & 15;
    const int xr  = r16 & 7;        // row&7 for all fragment rows this lane reads

    // staging map: thread t -> row srow (of 32 per issue), pre-swizzled 16B slot
    const int srow  = tid >> 3;
    const int sslot = (tid & 7) ^ (srow & 7);   // inverse-swizzle the SOURCE

    f32x4 acc[4][4] = {};   // acc[i][j]: i = K subtile, j = Q subtile

    for (int k0 = 0; k0 < DIM; k0 += 64) {
        #pragma unroll
        for (int i = 0; i < 4; ++i) {
            const int r = i * 32 + srow;
            const unsigned short* gq = qb + (size_t)(rowBase + r) * DIM + k0 + sslot * 8;
            const unsigned short* gk = kb + (size_t)(colBase + r) * DIM + k0 + sslot * 8;
            __builtin_amdgcn_global_load_lds(
                (const __attribute__((address_space(1))) void*)gq,
                (__attribute__((address_space(3))) void*)((char*)Qs + i * 4096 + wid * 1024),
                16, 0, 0);
            __builtin_amdgcn_global_load_lds(
                (const __attribute__((address_space(1))) void*)gk,
                (__attribute__((address_space(3))) void*)((char*)Ks + i * 4096 + wid * 1024),
                16, 0, 0);
        }
        __syncthreads();

        #pragma unroll
        for (int kk = 0; kk < 2; ++kk) {
            bf16x8 a[4], b[4];
            #pragma unroll
            for (int i = 0; i < 4; ++i) {   // A = K rows
                const int row = waveK * 64 + i * 16 + r16;
                a[i] = *reinterpret_cast<const bf16x8*>(
                    (const char*)Ks + row * 128 + ((((kk << 2) | g) ^ xr) << 4));
            }
            #pragma unroll
            for (int j = 0; j < 4; ++j) {   // B = Q rows
                const int row = waveQ * 64 + j * 16 + r16;
                b[j] = *reinterpret_cast<const bf16x8*>(
                    (const char*)Qs + row * 128 + ((((kk << 2) | g) ^ xr) << 4));
            }
            #pragma unroll
            for (int i = 0; i < 4; ++i)
                #pragma unroll
                for (int j = 0; j < 4; ++j)
                    acc[i][j] = __builtin_amdgcn_mfma_f32_16x16x32_bf16(a[i], b[j], acc[i][j], 0, 0, 0);
        }
        __syncthreads();
    }

    // ---- epilogue: lane-local fixed-max exp sums ----
    // acc[i][j][reg] = K_row(colBase + waveK*64 + i*16 + g*4 + reg) . Q_row(rowBase + waveQ*64 + j*16 + r16)
    #pragma unroll
    for (int j = 0; j < 4; ++j) {
        const int qrow_local = waveQ * 64 + j * 16 + r16;
        const int grow = rowBase + qrow_local;
        const float qs = invq[grow] * INV_T;
        float s = 0.0f;
        #pragma unroll
        for (int i = 0; i < 4; ++i) {
            const int colb = colBase + waveK * 64 + i * 16 + g * 4;
            const float4 ik4 = *reinterpret_cast<const float4*>(&invk[colb]);
            #pragma unroll
            for (int reg = 0; reg < 4; ++reg) {
                const float ik = (reg == 0) ? ik4.x : (reg == 1) ? ik4.y : (reg == 2) ? ik4.z : ik4.w;
                float v = acc[i][j][reg] * qs * ik;
                float e = __expf(v - M0);
                if (grow == colb + reg) e = 0.0f;   // diagonal: exp(-10/T - M0) == 0 anyway
                s += e;
            }
        }
        s += __shfl_xor(s, 16, 64);
        s += __shfl_xor(s, 32, 64);
        if (g == 0) redS[qrow_local][waveK] = s;
    }
    __syncthreads();

    if (tid < 128) {
        const float S = redS[tid][0] + redS[tid][1];
        ps[(size_t)(rowBase + tid) * 64 + blockIdx.x] = S;
    }
}

// ---------------- Kernel 3: combine partials -> loss ----------------
__global__ __launch_bounds__(64) void finalize_kernel(
    const float* __restrict__ ps, const float* __restrict__ lposT,
    float* __restrict__ out) {
    const int row  = blockIdx.x;
    const int lane = threadIdx.x;

    float S = ps[(size_t)row * 64 + lane];
    #pragma unroll
    for (int off = 1; off < 64; off <<= 1)
        S += __shfl_xor(S, off, 64);

    const float lp = lposT[row];
    S += __expf(lp - M0);

    if (lane == 0) out[row] = M0 + logf(S) - lp;
}

extern "C" void kernel_launch(void* const* d_in, const int* in_sizes, int n_in,
                              void* d_out, int out_size, void* d_ws, size_t ws_size,
                              hipStream_t stream) {
    const float* q = (const float*)d_in[0];
    const float* k = (const float*)d_in[1];
    float* out = (float*)d_out;

    char* ws = (char*)d_ws;
    unsigned short* qb   = (unsigned short*)(ws);                       // 4 MB
    unsigned short* kb   = (unsigned short*)(ws + (4u << 20));          // 4 MB
    float*          invq = (float*)(ws + (8u << 20));                   // 32 KB
    float*          invk = (float*)(ws + (8u << 20) + (32u << 10));     // 32 KB
    float*          lpt  = (float*)(ws + (8u << 20) + (64u << 10));     // 32 KB
    float*          ps   = (float*)(ws + (8u << 20) + (96u << 10));     // 2 MB

    prep_kernel<<<N_ROWS, 64, 0, stream>>>(q, k, qb, kb, invq, invk, lpt);
    dim3 grid(N_ROWS / 128, N_ROWS / 128);
    gemm_lse_kernel<<<grid, 256, 0, stream>>>(qb, kb, invq, invk, ps);
    finalize_kernel<<<N_ROWS, 64, 0, stream>>>(ps, lpt, out);
}

// Round 3
// 55.682 us; speedup vs baseline: 1.7885x; 1.1599x over previous
//
#include <hip/hip_runtime.h>
#include <stdint.h>

#define N_ROWS 8192
#define DIM 256

constexpr float INV_T  = 1.0f / 0.07f;
constexpr float M0     = 1.0f / 0.07f;             // fixed LSE max: |cos| <= ~1
constexpr float LOG2E  = 1.44269504088896f;
constexpr float C1     = INV_T * LOG2E;            // exp arg scale (exp2 domain)
constexpr float C0     = -M0 * LOG2E;              // exp arg bias

typedef __bf16 bf16x8 __attribute__((ext_vector_type(8)));
typedef float  f32x4  __attribute__((ext_vector_type(4)));

__device__ inline unsigned short f32_to_bf16(float f) {
    union { float f; uint32_t u; } v; v.f = f;
    uint32_t u = v.u;
    u += 0x7FFFu + ((u >> 16) & 1u);   // round-to-nearest-even
    return (unsigned short)(u >> 16);
}

// ---------------- Kernel 1: normalize rows -> bf16, l_pos ----------------
__global__ __launch_bounds__(256) void prep_kernel(
    const float* __restrict__ q, const float* __restrict__ k,
    unsigned short* __restrict__ qb, unsigned short* __restrict__ kb,
    float* __restrict__ lposT) {
    const int wid  = threadIdx.x >> 6;
    const int lane = threadIdx.x & 63;
    const int row  = blockIdx.x * 4 + wid;

    const float4 qv = *reinterpret_cast<const float4*>(q + (size_t)row * DIM + lane * 4);
    const float4 kv = *reinterpret_cast<const float4*>(k + (size_t)row * DIM + lane * 4);

    float qq = qv.x*qv.x + qv.y*qv.y + qv.z*qv.z + qv.w*qv.w;
    float kk = kv.x*kv.x + kv.y*kv.y + kv.z*kv.z + kv.w*kv.w;
    float qk = qv.x*kv.x + qv.y*kv.y + qv.z*kv.z + qv.w*kv.w;

    #pragma unroll
    for (int off = 32; off > 0; off >>= 1) {
        qq += __shfl_xor(qq, off, 64);
        kk += __shfl_xor(kk, off, 64);
        qk += __shfl_xor(qk, off, 64);
    }
    const float iq = 1.0f / sqrtf(qq);
    const float ik = 1.0f / sqrtf(kk);

    ushort4 qs, ks;
    qs.x = f32_to_bf16(qv.x * iq); qs.y = f32_to_bf16(qv.y * iq);
    qs.z = f32_to_bf16(qv.z * iq); qs.w = f32_to_bf16(qv.w * iq);
    ks.x = f32_to_bf16(kv.x * ik); ks.y = f32_to_bf16(kv.y * ik);
    ks.z = f32_to_bf16(kv.z * ik); ks.w = f32_to_bf16(kv.w * ik);
    *reinterpret_cast<ushort4*>(qb + (size_t)row * DIM + lane * 4) = qs;
    *reinterpret_cast<ushort4*>(kb + (size_t)row * DIM + lane * 4) = ks;

    if (lane == 0) lposT[row] = qk * iq * ik * INV_T;
}

// ---------------- Kernel 2: persistent K-strip GEMM + fused exp-sum ----------
// A = K rows, B = Q rows (swapped) -> D col = lane&15 = Q row (lane-local sums).
// Each block: 128 Q-rows in registers, streams 1024 K-rows (8 chunks x 4 ksteps)
// through double-buffered LDS; one barrier per step; epilogue fused per chunk.
__global__ __launch_bounds__(256, 2) void gemm_lse_kernel(
    const unsigned short* __restrict__ qb, const unsigned short* __restrict__ kb,
    float* __restrict__ ps) {
    __shared__ char lds[2 * 16384 + 1024];
    char* const b0 = lds;
    char* const b1 = lds + 16384;
    float* const redS = (float*)(lds + 32768);

    const int tid   = threadIdx.x;
    const int lane  = tid & 63;
    const int wid   = tid >> 6;
    const int waveQ = wid & 1;       // Q half (B operand / D cols)
    const int waveK = wid >> 1;      // K half (A operand / D rows)
    const int g     = lane >> 4;
    const int r16   = lane & 15;
    const int xr    = r16 & 7;

    const int strip   = blockIdx.x;        // 0..7  (== XCD id by dispatch order)
    const int qtile   = blockIdx.y;        // 0..63
    const int qbase   = qtile * 128;
    const int kstrip0 = strip * 1024;

    // staging map: thread t -> row t/8, pre-swizzled 16B slot (t%8)^(row&7)
    const int srow  = tid >> 3;
    const int sslot = (tid & 7) ^ (srow & 7);
    const int ldsWaveOff = wid * 1024;     // wave-uniform LDS sub-base

    auto stage = [&](const unsigned short* base, int row0, int k0, char* dst) {
        #pragma unroll
        for (int i = 0; i < 4; ++i) {
            const unsigned short* gp = base + (size_t)(row0 + i * 32 + srow) * DIM + k0 + sslot * 8;
            __builtin_amdgcn_global_load_lds(
                (const __attribute__((address_space(1))) void*)gp,
                (__attribute__((address_space(3))) void*)(dst + i * 4096 + ldsWaveOff),
                16, 0, 0);
        }
    };
    auto frag = [&](const char* src, int row, int chunk8) -> bf16x8 {
        return *reinterpret_cast<const bf16x8*>(src + row * 128 + ((chunk8 ^ xr) << 4));
    };

    // ---- Phase A: load 128 Q-rows x 256 dims into registers (once) ----
    bf16x8 qf[8][4];   // [kstep*2+kk][j]
    stage(qb, qbase, 0, b0);
    __syncthreads();
    #pragma unroll
    for (int c = 0; c < 4; ++c) {
        if (c < 3) stage(qb, qbase, (c + 1) * 64, (c & 1) ? b0 : b1);
        else       stage(kb, kstrip0, 0, b0);          // prologue of K stream
        const char* src = (c & 1) ? b1 : b0;
        #pragma unroll
        for (int kk = 0; kk < 2; ++kk)
            #pragma unroll
            for (int j = 0; j < 4; ++j)
                qf[c * 2 + kk][j] = frag(src, waveQ * 64 + j * 16 + r16, kk * 4 + g);
        __syncthreads();
    }

    // ---- Phase B: 32-step pipelined K stream ----
    f32x4 acc[4][4] = {};
    float ssum[4] = {0.f, 0.f, 0.f, 0.f};

    #pragma unroll 1
    for (int chunk = 0; chunk < 8; ++chunk) {
        const int kbase_c = kstrip0 + chunk * 128;
        #pragma unroll
        for (int kstep = 0; kstep < 4; ++kstep) {
            // stage next step into the other buffer (issue-early)
            if (kstep < 3) {
                stage(kb, kbase_c, (kstep + 1) * 64, (kstep & 1) ? b0 : b1);
            } else if (chunk < 7) {
                stage(kb, kbase_c + 128, 0, b0);       // next chunk, kstep 0 (parity 0)
            }
            const char* src = (kstep & 1) ? b1 : b0;
            #pragma unroll
            for (int kk = 0; kk < 2; ++kk) {
                bf16x8 a[4];
                #pragma unroll
                for (int i = 0; i < 4; ++i)
                    a[i] = frag(src, waveK * 64 + i * 16 + r16, kk * 4 + g);
                #pragma unroll
                for (int i = 0; i < 4; ++i)
                    #pragma unroll
                    for (int j = 0; j < 4; ++j)
                        acc[i][j] = __builtin_amdgcn_mfma_f32_16x16x32_bf16(
                            a[i], qf[kstep * 2 + kk][j], acc[i][j], 0, 0, 0);
            }
            if (kstep == 3) {
                // ---- fused epilogue for this chunk (registers only) ----
                const bool diag = (strip * 8 + chunk) == qtile;
                if (diag) {
                    #pragma unroll
                    for (int j = 0; j < 4; ++j) {
                        const int grow = qbase + waveQ * 64 + j * 16 + r16;
                        float s = 0.f;
                        #pragma unroll
                        for (int i = 0; i < 4; ++i) {
                            const int colb = kbase_c + waveK * 64 + i * 16 + g * 4;
                            #pragma unroll
                            for (int reg = 0; reg < 4; ++reg) {
                                float e = exp2f(fmaf(acc[i][j][reg], C1, C0));
                                if (grow == colb + reg) e = 0.f;
                                s += e;
                            }
                        }
                        ssum[j] += s;
                    }
                } else {
                    #pragma unroll
                    for (int j = 0; j < 4; ++j) {
                        float s = 0.f;
                        #pragma unroll
                        for (int i = 0; i < 4; ++i)
                            #pragma unroll
                            for (int reg = 0; reg < 4; ++reg)
                                s += exp2f(fmaf(acc[i][j][reg], C1, C0));
                        ssum[j] += s;
                    }
                }
                #pragma unroll
                for (int i = 0; i < 4; ++i)
                    #pragma unroll
                    for (int j = 0; j < 4; ++j)
                        acc[i][j] = f32x4{0.f, 0.f, 0.f, 0.f};
            }
            __syncthreads();   // one barrier per step: next data landed + cur buf free
        }
    }

    // ---- block reduction: combine g-groups and waveK halves ----
    #pragma unroll
    for (int j = 0; j < 4; ++j) {
        float s = ssum[j];
        s += __shfl_xor(s, 16, 64);
        s += __shfl_xor(s, 32, 64);
        if (g == 0) redS[(waveQ * 64 + j * 16 + r16) * 2 + waveK] = s;
    }
    __syncthreads();
    if (tid < 128)
        ps[(size_t)(qbase + tid) * 8 + strip] = redS[tid * 2] + redS[tid * 2 + 1];
}

// ---------------- Kernel 3: combine 8 strip partials -> loss ----------------
__global__ __launch_bounds__(256) void finalize_kernel(
    const float* __restrict__ ps, const float* __restrict__ lposT,
    float* __restrict__ out) {
    const int row = blockIdx.x * 256 + threadIdx.x;
    const float4 p0 = *reinterpret_cast<const float4*>(ps + (size_t)row * 8);
    const float4 p1 = *reinterpret_cast<const float4*>(ps + (size_t)row * 8 + 4);
    float S = p0.x + p0.y + p0.z + p0.w + p1.x + p1.y + p1.z + p1.w;
    const float lp = lposT[row];
    S += __expf(lp - M0);
    out[row] = M0 + logf(S) - lp;
}

extern "C" void kernel_launch(void* const* d_in, const int* in_sizes, int n_in,
                              void* d_out, int out_size, void* d_ws, size_t ws_size,
                              hipStream_t stream) {
    const float* q = (const float*)d_in[0];
    const float* k = (const float*)d_in[1];
    float* out = (float*)d_out;

    char* ws = (char*)d_ws;
    unsigned short* qb  = (unsigned short*)(ws);                      // 4 MB
    unsigned short* kb  = (unsigned short*)(ws + (4u << 20));         // 4 MB
    float*          lpt = (float*)(ws + (8u << 20));                  // 32 KB
    float*          ps  = (float*)(ws + (8u << 20) + (32u << 10));    // 256 KB

    prep_kernel<<<N_ROWS / 4, 256, 0, stream>>>(q, k, qb, kb, lpt);
    dim3 grid(8, 64);   // x = strip (-> XCD), y = Q-tile
    gemm_lse_kernel<<<grid, 256, 0, stream>>>(qb, kb, ps);
    finalize_kernel<<<N_ROWS / 256, 256, 0, stream>>>(ps, lpt, out);
}